// Round 1
// baseline (786.640 us; speedup 1.0000x reference)
//
#include <hip/hip_runtime.h>
#include <hip/hip_bf16.h>

// SupplyChainGNN: 3-layer GCN, N=50000, E=800000, H=64.
// Baseline round 0: atomic scatter-add aggregation (wave-per-edge, lane=feature).
// d_ws layout: bufA (N*64 f32, h/agg), bufB (N*64 f32, hw), dinv (N f32) = 25.8 MB.

#define HDIM 64

__global__ __launch_bounds__(256) void deg_init(float* __restrict__ deg, int N) {
    int i = blockIdx.x * 256 + threadIdx.x;
    if (i < N) deg[i] = 1.0f;  // self-loop
}

__global__ __launch_bounds__(256) void deg_count(const int* __restrict__ col, float* __restrict__ deg, int E) {
    int e = blockIdx.x * 256 + threadIdx.x;
    if (e < E) atomicAdd(&deg[col[e]], 1.0f);
}

__global__ __launch_bounds__(256) void deg_rsqrt(float* __restrict__ deg, int N) {
    int i = blockIdx.x * 256 + threadIdx.x;
    if (i < N) deg[i] = rsqrtf(deg[i]);
}

// h[i][j] = relu(sum_k x[i][k] * W_enc[k][j] + b_enc[j]);  x: [N,5], W: [5,64]
__global__ __launch_bounds__(256) void encoder(const float* __restrict__ x,
                                               const float* __restrict__ W,
                                               const float* __restrict__ b,
                                               float* __restrict__ h, int N) {
    int t = blockIdx.x * 256 + threadIdx.x;
    int i = t >> 6, j = t & 63;
    if (i >= N) return;
    float acc = b[j];
#pragma unroll
    for (int k = 0; k < 5; k++) acc = fmaf(x[i * 5 + k], W[k * 64 + j], acc);
    h[t] = fmaxf(acc, 0.0f);
}

// hw = h @ W (64x64); also init agg with the self-loop term hw[i]*dinv[i]^2.
// Block = 4 nodes x 64 features. Safe to overwrite agg (aliases h's buffer? no -
// here agg is a separate pointer but may alias h only per-row, and each row is
// staged to LDS before any write).
__global__ __launch_bounds__(256) void conv_matmul(const float* __restrict__ h,
                                                   const float* __restrict__ W,
                                                   const float* __restrict__ dinv,
                                                   float* __restrict__ hw,
                                                   float* __restrict__ agg, int N) {
    __shared__ float Ws[64 * 64];
    __shared__ float hs[4][64];
    int tid = threadIdx.x;
    const float4* W4 = (const float4*)W;
    float4* Ws4 = (float4*)Ws;
#pragma unroll
    for (int r = 0; r < 4; r++) Ws4[r * 256 + tid] = W4[r * 256 + tid];
    int nl = tid >> 6, j = tid & 63;
    int i = blockIdx.x * 4 + nl;
    hs[nl][j] = (i < N) ? h[i * 64 + j] : 0.0f;
    __syncthreads();
    if (i >= N) return;
    float acc = 0.0f;
#pragma unroll
    for (int k = 0; k < 64; k++) acc = fmaf(hs[nl][k], Ws[k * 64 + j], acc);
    hw[i * 64 + j] = acc;
    float di = dinv[i];
    agg[i * 64 + j] = acc * di * di;
}

// One wave per edge: lane = feature. agg[col] += hw[row] * dinv[row]*dinv[col]
__global__ __launch_bounds__(256) void edge_scatter(const int* __restrict__ ei,
                                                    const float* __restrict__ hw,
                                                    const float* __restrict__ dinv,
                                                    float* __restrict__ agg, int E) {
    int t = blockIdx.x * 256 + threadIdx.x;
    int e = t >> 6, lane = t & 63;
    if (e >= E) return;
    int r = ei[e];
    int c = ei[E + e];
    float w = dinv[r] * dinv[c];
    float v = hw[r * 64 + lane] * w;
    atomicAdd(&agg[c * 64 + lane], v);
}

// h = relu(agg + b[l]) in place, float4-vectorized.
__global__ __launch_bounds__(256) void relu_bias(float4* __restrict__ h, const float* __restrict__ b, int n4) {
    int t = blockIdx.x * 256 + threadIdx.x;
    if (t >= n4) return;
    float4 v = h[t];
    int j = (t * 4) & 63;
    v.x = fmaxf(v.x + b[j + 0], 0.0f);
    v.y = fmaxf(v.y + b[j + 1], 0.0f);
    v.z = fmaxf(v.z + b[j + 2], 0.0f);
    v.w = fmaxf(v.w + b[j + 3], 0.0f);
    h[t] = v;
}

// Two-head MLP. One wave per node: lanes 0-31 demand hidden, 32-63 inventory
// hidden. Butterfly-reduce each 32-half, write out[i] / out[N+i].
__global__ __launch_bounds__(256) void heads(const float* __restrict__ h,
                                             const float* __restrict__ W_d1, const float* __restrict__ b_d1,
                                             const float* __restrict__ W_d2, const float* __restrict__ b_d2,
                                             const float* __restrict__ W_i1, const float* __restrict__ b_i1,
                                             const float* __restrict__ W_i2, const float* __restrict__ b_i2,
                                             float* __restrict__ out, int N) {
    __shared__ float Wd[64 * 32];
    __shared__ float Wi[64 * 32];
    __shared__ float hs[4][64];
    int tid = threadIdx.x;
    {
        const float4* a = (const float4*)W_d1;
        float4* s = (float4*)Wd;
#pragma unroll
        for (int r = 0; r < 2; r++) s[r * 256 + tid] = a[r * 256 + tid];
        a = (const float4*)W_i1;
        s = (float4*)Wi;
#pragma unroll
        for (int r = 0; r < 2; r++) s[r * 256 + tid] = a[r * 256 + tid];
    }
    int nl = tid >> 6, lane = tid & 63;
    int i = blockIdx.x * 4 + nl;
    hs[nl][lane] = (i < N) ? h[i * 64 + lane] : 0.0f;
    __syncthreads();
    if (i >= N) return;
    bool dem = lane < 32;
    int j = dem ? lane : lane - 32;
    const float* W1 = dem ? Wd : Wi;
    float acc = dem ? b_d1[j] : b_i1[j];
#pragma unroll
    for (int k = 0; k < 64; k++) acc = fmaf(hs[nl][k], W1[k * 32 + j], acc);
    acc = fmaxf(acc, 0.0f);
    float t2 = acc * (dem ? W_d2[j] : W_i2[j]);
#pragma unroll
    for (int off = 16; off >= 1; off >>= 1) t2 += __shfl_xor(t2, off, 64);
    if (j == 0) {
        out[(dem ? 0 : N) + i] = t2 + (dem ? b_d2[0] : b_i2[0]);
    }
}

extern "C" void kernel_launch(void* const* d_in, const int* in_sizes, int n_in,
                              void* d_out, int out_size, void* d_ws, size_t ws_size,
                              hipStream_t stream) {
    const float* x      = (const float*)d_in[0];
    const int*   ei     = (const int*)d_in[1];   // [2, E] int (harness converts integer -> int32)
    const float* W_enc  = (const float*)d_in[2];
    const float* b_enc  = (const float*)d_in[3];
    const float* conv_W = (const float*)d_in[4]; // [3, 64, 64]
    const float* conv_b = (const float*)d_in[5]; // [3, 64]
    const float* W_d1   = (const float*)d_in[6];
    const float* b_d1   = (const float*)d_in[7];
    const float* W_d2   = (const float*)d_in[8];
    const float* b_d2   = (const float*)d_in[9];
    const float* W_i1   = (const float*)d_in[10];
    const float* b_i1   = (const float*)d_in[11];
    const float* W_i2   = (const float*)d_in[12];
    const float* b_i2   = (const float*)d_in[13];

    const int N = in_sizes[0] / 5;
    const int E = in_sizes[1] / 2;

    float* bufA = (float*)d_ws;                 // h / agg  [N*64]
    float* bufB = bufA + (size_t)N * HDIM;      // hw       [N*64]
    float* dinv = bufB + (size_t)N * HDIM;      // deg -> dinv [N]
    float* out  = (float*)d_out;

    const int nodeBlocks = (N + 255) / 256;
    const int edgeBlocks = (E + 255) / 256;
    const int nwBlocks   = (N + 3) / 4;          // 4 nodes (waves) per block
    const int ewBlocks   = (E + 3) / 4;          // 4 edges (waves) per block
    const int n4Blocks   = ((N * HDIM / 4) + 255) / 256;

    // degree + norm
    deg_init<<<nodeBlocks, 256, 0, stream>>>(dinv, N);
    deg_count<<<edgeBlocks, 256, 0, stream>>>(ei + E, dinv, E);  // col = second row
    deg_rsqrt<<<nodeBlocks, 256, 0, stream>>>(dinv, N);

    // encoder
    encoder<<<(N * HDIM + 255) / 256, 256, 0, stream>>>(x, W_enc, b_enc, bufA, N);

    // 3 GCN layers
    for (int l = 0; l < 3; l++) {
        conv_matmul<<<nwBlocks, 256, 0, stream>>>(bufA, conv_W + l * HDIM * HDIM, dinv, bufB, bufA, N);
        edge_scatter<<<ewBlocks, 256, 0, stream>>>(ei, bufB, dinv, bufA, E);
        relu_bias<<<n4Blocks, 256, 0, stream>>>((float4*)bufA, conv_b + l * HDIM, N * HDIM / 4);
    }

    // heads
    heads<<<nwBlocks, 256, 0, stream>>>(bufA, W_d1, b_d1, W_d2, b_d2, W_i1, b_i1, W_i2, b_i2, out, N);
}

// Round 2
// 684.701 us; speedup vs baseline: 1.1489x; 1.1489x over previous
//
#include <hip/hip_runtime.h>
#include <hip/hip_bf16.h>

// SupplyChainGNN: 3-layer GCN, N=50000, E=800000, H=64.
// Round 1: replace atomic scatter with CSR (counting sort by col) + register
// gather. Fuses relu+bias+self-loop into gather; dinv from CSR counts.
// d_ws layout: bufA(h) 12.8MB, bufB(hwn) 12.8MB, dinv 200KB, cnt 200KB,
// row_ptr 200KB+4, fill 200KB, csr_src 3.2MB  (~29.6MB total).

#define HDIM 64

__global__ __launch_bounds__(256) void zero_cnt(unsigned int* __restrict__ cnt, int N) {
    int i = blockIdx.x * 256 + threadIdx.x;
    if (i < N) cnt[i] = 0u;
}

__global__ __launch_bounds__(256) void count_col(const int* __restrict__ col,
                                                 unsigned int* __restrict__ cnt, int E) {
    int e = blockIdx.x * 256 + threadIdx.x;
    if (e < E) atomicAdd(&cnt[col[e]], 1u);
}

// Single-block exclusive scan of cnt -> row_ptr; also dinv[i]=rsqrt(cnt[i]+1)
// (deg includes self-loop) and zeroes the fill cursors.
__global__ __launch_bounds__(256) void scan_csr(const unsigned int* __restrict__ cnt,
                                                unsigned int* __restrict__ row_ptr,
                                                float* __restrict__ dinv,
                                                unsigned int* __restrict__ fill,
                                                int N, int E) {
    __shared__ unsigned int part[256];
    int t = threadIdx.x;
    int chunk = (N + 255) / 256;
    int lo = t * chunk;
    int hi = lo + chunk; if (hi > N) hi = N;
    unsigned int s = 0;
    for (int i = lo; i < hi; i++) s += cnt[i];
    part[t] = s;
    __syncthreads();
    for (int off = 1; off < 256; off <<= 1) {
        unsigned int u = (t >= off) ? part[t - off] : 0u;
        __syncthreads();
        part[t] += u;
        __syncthreads();
    }
    unsigned int run = part[t] - s;  // exclusive base for this chunk
    for (int i = lo; i < hi; i++) {
        unsigned int c = cnt[i];
        row_ptr[i] = run;
        dinv[i] = rsqrtf((float)(c + 1u));
        fill[i] = 0u;
        run += c;
    }
    if (t == 0) row_ptr[N] = (unsigned int)E;
}

__global__ __launch_bounds__(256) void fill_csr(const int* __restrict__ ei,
                                                const unsigned int* __restrict__ row_ptr,
                                                unsigned int* __restrict__ fill,
                                                int* __restrict__ csr_src, int E) {
    int e = blockIdx.x * 256 + threadIdx.x;
    if (e >= E) return;
    int r = ei[e];
    int c = ei[E + e];
    unsigned int ofs = atomicAdd(&fill[c], 1u);
    csr_src[row_ptr[c] + ofs] = r;
}

// h[i][j] = relu(sum_k x[i][k] * W_enc[k][j] + b_enc[j]);  x: [N,5], W: [5,64]
__global__ __launch_bounds__(256) void encoder(const float* __restrict__ x,
                                               const float* __restrict__ W,
                                               const float* __restrict__ b,
                                               float* __restrict__ h, int N) {
    int t = blockIdx.x * 256 + threadIdx.x;
    int i = t >> 6, j = t & 63;
    if (i >= N) return;
    float acc = b[j];
#pragma unroll
    for (int k = 0; k < 5; k++) acc = fmaf(x[i * 5 + k], W[k * 64 + j], acc);
    h[t] = fmaxf(acc, 0.0f);
}

// hwn[i] = (h @ W)[i] * dinv[i].  Block = 256 thr = 4 waves, each wave does
// CNODES nodes via shfl-broadcast of its h row (amortizes the 16KB W LDS load).
#define CNODES 4
__global__ __launch_bounds__(256) void conv_matmul(const float* __restrict__ h,
                                                   const float* __restrict__ W,
                                                   const float* __restrict__ dinv,
                                                   float* __restrict__ hwn, int N) {
    __shared__ float Ws[64 * 64];
    int tid = threadIdx.x;
    {
        const float4* W4 = (const float4*)W;
        float4* Ws4 = (float4*)Ws;
#pragma unroll
        for (int r = 0; r < 4; r++) Ws4[r * 256 + tid] = W4[r * 256 + tid];
    }
    __syncthreads();
    int wave = tid >> 6, lane = tid & 63;
    int base = (blockIdx.x * 4 + wave) * CNODES;
#pragma unroll
    for (int n = 0; n < CNODES; n++) {
        int i = base + n;
        if (i >= N) break;
        float hv = h[(size_t)i * 64 + lane];
        float acc = 0.0f;
#pragma unroll
        for (int k = 0; k < 64; k++) acc = fmaf(__shfl(hv, k, 64), Ws[k * 64 + lane], acc);
        hwn[(size_t)i * 64 + lane] = acc * dinv[i];
    }
}

// One wave per node: h_out[i] = relu(dinv[i]*(hwn[i] + sum_{s in src(i)} hwn[s]) + b)
__global__ __launch_bounds__(256) void gather(const unsigned int* __restrict__ row_ptr,
                                              const int* __restrict__ csr_src,
                                              const float* __restrict__ hwn,
                                              const float* __restrict__ dinv,
                                              const float* __restrict__ b,
                                              float* __restrict__ hout, int N) {
    int t = blockIdx.x * 256 + threadIdx.x;
    int i = t >> 6, lane = t & 63;
    if (i >= N) return;
    float acc = hwn[(size_t)i * 64 + lane];  // self-loop term
    unsigned int e = row_ptr[i], e1 = row_ptr[i + 1];
    for (; e + 2 <= e1; e += 2) {            // 2-way ILP on the row loads
        int s0 = csr_src[e];
        int s1 = csr_src[e + 1];
        float a0 = hwn[(size_t)s0 * 64 + lane];
        float a1 = hwn[(size_t)s1 * 64 + lane];
        acc += a0;
        acc += a1;
    }
    if (e < e1) acc += hwn[(size_t)csr_src[e] * 64 + lane];
    hout[(size_t)i * 64 + lane] = fmaxf(fmaf(dinv[i], acc, b[lane]), 0.0f);
}

// Two-head MLP. Wave per HNODES nodes: lanes 0-31 demand hidden, 32-63
// inventory hidden; shfl-broadcast h row; butterfly-reduce each 32-half.
#define HNODES 8
__global__ __launch_bounds__(256) void heads(const float* __restrict__ h,
                                             const float* __restrict__ W_d1, const float* __restrict__ b_d1,
                                             const float* __restrict__ W_d2, const float* __restrict__ b_d2,
                                             const float* __restrict__ W_i1, const float* __restrict__ b_i1,
                                             const float* __restrict__ W_i2, const float* __restrict__ b_i2,
                                             float* __restrict__ out, int N) {
    __shared__ float Wd[64 * 32];
    __shared__ float Wi[64 * 32];
    int tid = threadIdx.x;
    {
        const float4* a = (const float4*)W_d1;
        float4* sm = (float4*)Wd;
        sm[tid] = a[tid];
        sm[256 + tid] = a[256 + tid];
        a = (const float4*)W_i1;
        sm = (float4*)Wi;
        sm[tid] = a[tid];
        sm[256 + tid] = a[256 + tid];
    }
    __syncthreads();
    int wave = tid >> 6, lane = tid & 63;
    bool dem = lane < 32;
    int j = lane & 31;
    const float* W1 = dem ? Wd : Wi;
    float w2 = dem ? W_d2[j] : W_i2[j];
    float b1 = dem ? b_d1[j] : b_i1[j];
    float b2 = dem ? b_d2[0] : b_i2[0];
    int base = (blockIdx.x * 4 + wave) * HNODES;
#pragma unroll
    for (int n = 0; n < HNODES; n++) {
        int i = base + n;
        if (i >= N) break;
        float hv = h[(size_t)i * 64 + lane];
        float acc = b1;
#pragma unroll
        for (int k = 0; k < 64; k++) acc = fmaf(__shfl(hv, k, 64), W1[k * 32 + j], acc);
        acc = fmaxf(acc, 0.0f) * w2;
#pragma unroll
        for (int off = 16; off >= 1; off >>= 1) acc += __shfl_xor(acc, off, 64);
        if (j == 0) out[(dem ? 0 : N) + i] = acc + b2;
    }
}

extern "C" void kernel_launch(void* const* d_in, const int* in_sizes, int n_in,
                              void* d_out, int out_size, void* d_ws, size_t ws_size,
                              hipStream_t stream) {
    const float* x      = (const float*)d_in[0];
    const int*   ei     = (const int*)d_in[1];   // [2, E] int32
    const float* W_enc  = (const float*)d_in[2];
    const float* b_enc  = (const float*)d_in[3];
    const float* conv_W = (const float*)d_in[4]; // [3, 64, 64]
    const float* conv_b = (const float*)d_in[5]; // [3, 64]
    const float* W_d1   = (const float*)d_in[6];
    const float* b_d1   = (const float*)d_in[7];
    const float* W_d2   = (const float*)d_in[8];
    const float* b_d2   = (const float*)d_in[9];
    const float* W_i1   = (const float*)d_in[10];
    const float* b_i1   = (const float*)d_in[11];
    const float* W_i2   = (const float*)d_in[12];
    const float* b_i2   = (const float*)d_in[13];

    const int N = in_sizes[0] / 5;
    const int E = in_sizes[1] / 2;

    float* bufA = (float*)d_ws;                         // h  [N*64]
    float* bufB = bufA + (size_t)N * HDIM;              // hwn [N*64]
    float* dinv = bufB + (size_t)N * HDIM;              // [N]
    unsigned int* cnt     = (unsigned int*)(dinv + N);  // [N]
    unsigned int* row_ptr = cnt + N;                    // [N+1]
    unsigned int* fillc   = row_ptr + N + 1;            // [N]
    int* csr_src          = (int*)(fillc + N);          // [E]
    float* out = (float*)d_out;

    const int nodeBlocks = (N + 255) / 256;
    const int edgeBlocks = (E + 255) / 256;
    const int nwBlocks   = (N + 3) / 4;                  // wave per node
    const int convBlocks = (N + 4 * CNODES - 1) / (4 * CNODES);
    const int headBlocks = (N + 4 * HNODES - 1) / (4 * HNODES);

    // CSR build (counting sort by destination) + dinv
    zero_cnt<<<nodeBlocks, 256, 0, stream>>>(cnt, N);
    count_col<<<edgeBlocks, 256, 0, stream>>>(ei + E, cnt, E);
    scan_csr<<<1, 256, 0, stream>>>(cnt, row_ptr, dinv, fillc, N, E);
    fill_csr<<<edgeBlocks, 256, 0, stream>>>(ei, row_ptr, fillc, csr_src, E);

    // encoder
    encoder<<<(N * HDIM + 255) / 256, 256, 0, stream>>>(x, W_enc, b_enc, bufA, N);

    // 3 GCN layers: matmul+scale, then gather (fused self-loop+bias+relu)
    for (int l = 0; l < 3; l++) {
        conv_matmul<<<convBlocks, 256, 0, stream>>>(bufA, conv_W + l * HDIM * HDIM, dinv, bufB, N);
        gather<<<nwBlocks, 256, 0, stream>>>(row_ptr, csr_src, bufB, dinv, conv_b + l * HDIM, bufA, N);
    }

    // heads
    heads<<<headBlocks, 256, 0, stream>>>(bufA, W_d1, b_d1, W_d2, b_d2, W_i1, b_i1, W_i2, b_i2, out, N);
}

// Round 3
// 503.128 us; speedup vs baseline: 1.5635x; 1.3609x over previous
//
#include <hip/hip_runtime.h>
#include <hip/hip_bf16.h>

// SupplyChainGNN: 3-layer GCN, N=50000, E=800000, H=64.
// Round 2: parallel 3-phase CSR scan (was 148us single-block -> ~12us),
// 4-way ILP in gather.
// d_ws layout: bufA(h) 12.8MB, bufB(hwn) 12.8MB, dinv 200KB, cnt 200KB,
// row_ptr 200KB+4, fill 200KB, bsum 4KB, csr_src 3.2MB (~29.6MB total).

#define HDIM 64

__global__ __launch_bounds__(256) void zero_cnt(unsigned int* __restrict__ cnt, int N) {
    int i = blockIdx.x * 256 + threadIdx.x;
    if (i < N) cnt[i] = 0u;
}

__global__ __launch_bounds__(256) void count_col(const int* __restrict__ col,
                                                 unsigned int* __restrict__ cnt, int E) {
    int e = blockIdx.x * 256 + threadIdx.x;
    if (e < E) atomicAdd(&cnt[col[e]], 1u);
}

// Phase A: per-block reduce of cnt -> bsum[block]
__global__ __launch_bounds__(256) void scan_blocks(const unsigned int* __restrict__ cnt,
                                                   unsigned int* __restrict__ bsum, int N) {
    __shared__ unsigned int s[256];
    int t = threadIdx.x;
    int i = blockIdx.x * 256 + t;
    unsigned int v = (i < N) ? cnt[i] : 0u;
    s[t] = v;
    __syncthreads();
#pragma unroll
    for (int off = 128; off >= 1; off >>= 1) {
        if (t < off) s[t] += s[t + off];
        __syncthreads();
    }
    if (t == 0) bsum[blockIdx.x] = s[0];
}

// Phase B: single-block exclusive scan of bsum (nb <= 256*chunk, serial chunk)
__global__ __launch_bounds__(256) void scan_top(unsigned int* __restrict__ bsum, int nb) {
    __shared__ unsigned int part[256];
    int t = threadIdx.x;
    int chunk = (nb + 255) / 256;
    int lo = t * chunk, hi = lo + chunk;
    if (hi > nb) hi = nb;
    unsigned int s = 0;
    for (int i = lo; i < hi; i++) s += bsum[i];
    part[t] = s;
    __syncthreads();
    for (int off = 1; off < 256; off <<= 1) {
        unsigned int u = (t >= off) ? part[t - off] : 0u;
        __syncthreads();
        part[t] += u;
        __syncthreads();
    }
    unsigned int run = part[t] - s;  // exclusive base
    for (int i = lo; i < hi; i++) {
        unsigned int c = bsum[i];
        bsum[i] = run;
        run += c;
    }
}

// Phase C: local Hillis-Steele scan + block base -> row_ptr; fused dinv/fill init.
__global__ __launch_bounds__(256) void scan_finish(const unsigned int* __restrict__ cnt,
                                                   const unsigned int* __restrict__ bsum,
                                                   unsigned int* __restrict__ row_ptr,
                                                   float* __restrict__ dinv,
                                                   unsigned int* __restrict__ fill,
                                                   int N, int E) {
    __shared__ unsigned int s[256];
    int t = threadIdx.x;
    int i = blockIdx.x * 256 + t;
    unsigned int v = (i < N) ? cnt[i] : 0u;
    s[t] = v;
    __syncthreads();
    for (int off = 1; off < 256; off <<= 1) {
        unsigned int u = (t >= off) ? s[t - off] : 0u;
        __syncthreads();
        s[t] += u;
        __syncthreads();
    }
    if (i < N) {
        unsigned int ex = s[t] - v + bsum[blockIdx.x];
        row_ptr[i] = ex;
        dinv[i] = rsqrtf((float)(v + 1u));
        fill[i] = 0u;
        if (i == N - 1) row_ptr[N] = (unsigned int)E;
    }
}

__global__ __launch_bounds__(256) void fill_csr(const int* __restrict__ ei,
                                                const unsigned int* __restrict__ row_ptr,
                                                unsigned int* __restrict__ fill,
                                                int* __restrict__ csr_src, int E) {
    int e = blockIdx.x * 256 + threadIdx.x;
    if (e >= E) return;
    int r = ei[e];
    int c = ei[E + e];
    unsigned int ofs = atomicAdd(&fill[c], 1u);
    csr_src[row_ptr[c] + ofs] = r;
}

// h[i][j] = relu(sum_k x[i][k] * W_enc[k][j] + b_enc[j]);  x: [N,5], W: [5,64]
__global__ __launch_bounds__(256) void encoder(const float* __restrict__ x,
                                               const float* __restrict__ W,
                                               const float* __restrict__ b,
                                               float* __restrict__ h, int N) {
    int t = blockIdx.x * 256 + threadIdx.x;
    int i = t >> 6, j = t & 63;
    if (i >= N) return;
    float acc = b[j];
#pragma unroll
    for (int k = 0; k < 5; k++) acc = fmaf(x[i * 5 + k], W[k * 64 + j], acc);
    h[t] = fmaxf(acc, 0.0f);
}

// hwn[i] = (h @ W)[i] * dinv[i].  Block = 256 thr = 4 waves, each wave does
// CNODES nodes via shfl-broadcast of its h row (amortizes the 16KB W LDS load).
#define CNODES 4
__global__ __launch_bounds__(256) void conv_matmul(const float* __restrict__ h,
                                                   const float* __restrict__ W,
                                                   const float* __restrict__ dinv,
                                                   float* __restrict__ hwn, int N) {
    __shared__ float Ws[64 * 64];
    int tid = threadIdx.x;
    {
        const float4* W4 = (const float4*)W;
        float4* Ws4 = (float4*)Ws;
#pragma unroll
        for (int r = 0; r < 4; r++) Ws4[r * 256 + tid] = W4[r * 256 + tid];
    }
    __syncthreads();
    int wave = tid >> 6, lane = tid & 63;
    int base = (blockIdx.x * 4 + wave) * CNODES;
#pragma unroll
    for (int n = 0; n < CNODES; n++) {
        int i = base + n;
        if (i >= N) break;
        float hv = h[(size_t)i * 64 + lane];
        float acc = 0.0f;
#pragma unroll
        for (int k = 0; k < 64; k++) acc = fmaf(__shfl(hv, k, 64), Ws[k * 64 + lane], acc);
        hwn[(size_t)i * 64 + lane] = acc * dinv[i];
    }
}

// One wave per node: h_out[i] = relu(dinv[i]*(hwn[i] + sum_{s in src(i)} hwn[s]) + b)
__global__ __launch_bounds__(256) void gather(const unsigned int* __restrict__ row_ptr,
                                              const int* __restrict__ csr_src,
                                              const float* __restrict__ hwn,
                                              const float* __restrict__ dinv,
                                              const float* __restrict__ b,
                                              float* __restrict__ hout, int N) {
    int t = blockIdx.x * 256 + threadIdx.x;
    int i = t >> 6, lane = t & 63;
    if (i >= N) return;
    float acc = hwn[(size_t)i * 64 + lane];  // self-loop term
    unsigned int e = row_ptr[i], e1 = row_ptr[i + 1];
    for (; e + 4 <= e1; e += 4) {            // 4-way ILP on the row loads
        int s0 = csr_src[e];
        int s1 = csr_src[e + 1];
        int s2 = csr_src[e + 2];
        int s3 = csr_src[e + 3];
        float a0 = hwn[(size_t)s0 * 64 + lane];
        float a1 = hwn[(size_t)s1 * 64 + lane];
        float a2 = hwn[(size_t)s2 * 64 + lane];
        float a3 = hwn[(size_t)s3 * 64 + lane];
        acc += a0; acc += a1; acc += a2; acc += a3;
    }
    for (; e < e1; e++) acc += hwn[(size_t)csr_src[e] * 64 + lane];
    hout[(size_t)i * 64 + lane] = fmaxf(fmaf(dinv[i], acc, b[lane]), 0.0f);
}

// Two-head MLP. Wave per HNODES nodes: lanes 0-31 demand hidden, 32-63
// inventory hidden; shfl-broadcast h row; butterfly-reduce each 32-half.
#define HNODES 8
__global__ __launch_bounds__(256) void heads(const float* __restrict__ h,
                                             const float* __restrict__ W_d1, const float* __restrict__ b_d1,
                                             const float* __restrict__ W_d2, const float* __restrict__ b_d2,
                                             const float* __restrict__ W_i1, const float* __restrict__ b_i1,
                                             const float* __restrict__ W_i2, const float* __restrict__ b_i2,
                                             float* __restrict__ out, int N) {
    __shared__ float Wd[64 * 32];
    __shared__ float Wi[64 * 32];
    int tid = threadIdx.x;
    {
        const float4* a = (const float4*)W_d1;
        float4* sm = (float4*)Wd;
        sm[tid] = a[tid];
        sm[256 + tid] = a[256 + tid];
        a = (const float4*)W_i1;
        sm = (float4*)Wi;
        sm[tid] = a[tid];
        sm[256 + tid] = a[256 + tid];
    }
    __syncthreads();
    int wave = tid >> 6, lane = tid & 63;
    bool dem = lane < 32;
    int j = lane & 31;
    const float* W1 = dem ? Wd : Wi;
    float w2 = dem ? W_d2[j] : W_i2[j];
    float b1 = dem ? b_d1[j] : b_i1[j];
    float b2 = dem ? b_d2[0] : b_i2[0];
    int base = (blockIdx.x * 4 + wave) * HNODES;
#pragma unroll
    for (int n = 0; n < HNODES; n++) {
        int i = base + n;
        if (i >= N) break;
        float hv = h[(size_t)i * 64 + lane];
        float acc = b1;
#pragma unroll
        for (int k = 0; k < 64; k++) acc = fmaf(__shfl(hv, k, 64), W1[k * 32 + j], acc);
        acc = fmaxf(acc, 0.0f) * w2;
#pragma unroll
        for (int off = 16; off >= 1; off >>= 1) acc += __shfl_xor(acc, off, 64);
        if (j == 0) out[(dem ? 0 : N) + i] = acc + b2;
    }
}

extern "C" void kernel_launch(void* const* d_in, const int* in_sizes, int n_in,
                              void* d_out, int out_size, void* d_ws, size_t ws_size,
                              hipStream_t stream) {
    const float* x      = (const float*)d_in[0];
    const int*   ei     = (const int*)d_in[1];   // [2, E] int32
    const float* W_enc  = (const float*)d_in[2];
    const float* b_enc  = (const float*)d_in[3];
    const float* conv_W = (const float*)d_in[4]; // [3, 64, 64]
    const float* conv_b = (const float*)d_in[5]; // [3, 64]
    const float* W_d1   = (const float*)d_in[6];
    const float* b_d1   = (const float*)d_in[7];
    const float* W_d2   = (const float*)d_in[8];
    const float* b_d2   = (const float*)d_in[9];
    const float* W_i1   = (const float*)d_in[10];
    const float* b_i1   = (const float*)d_in[11];
    const float* W_i2   = (const float*)d_in[12];
    const float* b_i2   = (const float*)d_in[13];

    const int N = in_sizes[0] / 5;
    const int E = in_sizes[1] / 2;

    float* bufA = (float*)d_ws;                         // h  [N*64]
    float* bufB = bufA + (size_t)N * HDIM;              // hwn [N*64]
    float* dinv = bufB + (size_t)N * HDIM;              // [N]
    unsigned int* cnt     = (unsigned int*)(dinv + N);  // [N]
    unsigned int* row_ptr = cnt + N;                    // [N+1]
    unsigned int* fillc   = row_ptr + N + 1;            // [N]
    unsigned int* bsum    = fillc + N;                  // [nodeBlocks]
    int* csr_src          = (int*)(bsum + 1024);        // [E]
    float* out = (float*)d_out;

    const int nodeBlocks = (N + 255) / 256;
    const int edgeBlocks = (E + 255) / 256;
    const int nwBlocks   = (N + 3) / 4;                  // wave per node
    const int convBlocks = (N + 4 * CNODES - 1) / (4 * CNODES);
    const int headBlocks = (N + 4 * HNODES - 1) / (4 * HNODES);

    // CSR build (counting sort by destination) + dinv
    zero_cnt<<<nodeBlocks, 256, 0, stream>>>(cnt, N);
    count_col<<<edgeBlocks, 256, 0, stream>>>(ei + E, cnt, E);
    scan_blocks<<<nodeBlocks, 256, 0, stream>>>(cnt, bsum, N);
    scan_top<<<1, 256, 0, stream>>>(bsum, nodeBlocks);
    scan_finish<<<nodeBlocks, 256, 0, stream>>>(cnt, bsum, row_ptr, dinv, fillc, N, E);
    fill_csr<<<edgeBlocks, 256, 0, stream>>>(ei, row_ptr, fillc, csr_src, E);

    // encoder
    encoder<<<(N * HDIM + 255) / 256, 256, 0, stream>>>(x, W_enc, b_enc, bufA, N);

    // 3 GCN layers: matmul+scale, then gather (fused self-loop+bias+relu)
    for (int l = 0; l < 3; l++) {
        conv_matmul<<<convBlocks, 256, 0, stream>>>(bufA, conv_W + l * HDIM * HDIM, dinv, bufB, N);
        gather<<<nwBlocks, 256, 0, stream>>>(row_ptr, csr_src, bufB, dinv, conv_b + l * HDIM, bufA, N);
    }

    // heads
    heads<<<headBlocks, 256, 0, stream>>>(bufA, W_d1, b_d1, W_d2, b_d2, W_i1, b_i1, W_i2, b_i2, out, N);
}

// Round 4
// 363.780 us; speedup vs baseline: 2.1624x; 1.3831x over previous
//
#include <hip/hip_runtime.h>
#include <hip/hip_bf16.h>

// SupplyChainGNN: 3-layer GCN, N=50000, E=800000, H=64.
// Round 3: algebraic reorder (aggregate first, then W): hn = dinv*h;
// g = hn_i + sum hn_src; h_next = relu(dinv*(g@W)+b). Dense ops restructured
// as thread-per-node with row in VGPRs + LDS-transposed weights (broadcast
// ds_read_b128, wave-uniform indices) -- no shfl in inner loops.
// d_ws: bufA 12.8MB, bufB 12.8MB, dinv 200KB, cnt 200KB, row_ptr 200KB,
// fill 200KB, bsum 4KB, csr_src 3.2MB.

#define HDIM 64

__global__ __launch_bounds__(256) void zero_cnt(unsigned int* __restrict__ cnt, int N) {
    int i = blockIdx.x * 256 + threadIdx.x;
    if (i < N) cnt[i] = 0u;
}

__global__ __launch_bounds__(256) void count_col(const int* __restrict__ col,
                                                 unsigned int* __restrict__ cnt, int E) {
    int e = blockIdx.x * 256 + threadIdx.x;
    if (e < E) atomicAdd(&cnt[col[e]], 1u);
}

// Phase A: per-block reduce of cnt -> bsum[block]
__global__ __launch_bounds__(256) void scan_blocks(const unsigned int* __restrict__ cnt,
                                                   unsigned int* __restrict__ bsum, int N) {
    __shared__ unsigned int s[256];
    int t = threadIdx.x;
    int i = blockIdx.x * 256 + t;
    s[t] = (i < N) ? cnt[i] : 0u;
    __syncthreads();
#pragma unroll
    for (int off = 128; off >= 1; off >>= 1) {
        if (t < off) s[t] += s[t + off];
        __syncthreads();
    }
    if (t == 0) bsum[blockIdx.x] = s[0];
}

// Phase B: single-block exclusive scan of bsum
__global__ __launch_bounds__(256) void scan_top(unsigned int* __restrict__ bsum, int nb) {
    __shared__ unsigned int part[256];
    int t = threadIdx.x;
    int chunk = (nb + 255) / 256;
    int lo = t * chunk, hi = lo + chunk;
    if (hi > nb) hi = nb;
    unsigned int s = 0;
    for (int i = lo; i < hi; i++) s += bsum[i];
    part[t] = s;
    __syncthreads();
    for (int off = 1; off < 256; off <<= 1) {
        unsigned int u = (t >= off) ? part[t - off] : 0u;
        __syncthreads();
        part[t] += u;
        __syncthreads();
    }
    unsigned int run = part[t] - s;
    for (int i = lo; i < hi; i++) {
        unsigned int c = bsum[i];
        bsum[i] = run;
        run += c;
    }
}

// Phase C: local scan + block base -> row_ptr; fused dinv/fill init.
__global__ __launch_bounds__(256) void scan_finish(const unsigned int* __restrict__ cnt,
                                                   const unsigned int* __restrict__ bsum,
                                                   unsigned int* __restrict__ row_ptr,
                                                   float* __restrict__ dinv,
                                                   unsigned int* __restrict__ fill,
                                                   int N, int E) {
    __shared__ unsigned int s[256];
    int t = threadIdx.x;
    int i = blockIdx.x * 256 + t;
    unsigned int v = (i < N) ? cnt[i] : 0u;
    s[t] = v;
    __syncthreads();
    for (int off = 1; off < 256; off <<= 1) {
        unsigned int u = (t >= off) ? s[t - off] : 0u;
        __syncthreads();
        s[t] += u;
        __syncthreads();
    }
    if (i < N) {
        row_ptr[i] = s[t] - v + bsum[blockIdx.x];
        dinv[i] = rsqrtf((float)(v + 1u));
        fill[i] = 0u;
        if (i == N - 1) row_ptr[N] = (unsigned int)E;
    }
}

__global__ __launch_bounds__(256) void fill_csr(const int* __restrict__ ei,
                                                const unsigned int* __restrict__ row_ptr,
                                                unsigned int* __restrict__ fill,
                                                int* __restrict__ csr_src, int E) {
    int e = blockIdx.x * 256 + threadIdx.x;
    if (e >= E) return;
    int r = ei[e];
    int c = ei[E + e];
    unsigned int ofs = atomicAdd(&fill[c], 1u);
    csr_src[row_ptr[c] + ofs] = r;
}

// hn[i][j] = dinv[i] * relu(sum_k x[i][k]*W[k][j] + b[j]); x:[N,5]
__global__ __launch_bounds__(256) void encoder(const float* __restrict__ x,
                                               const float* __restrict__ W,
                                               const float* __restrict__ b,
                                               const float* __restrict__ dinv,
                                               float* __restrict__ hn, int N) {
    int t = blockIdx.x * 256 + threadIdx.x;
    int i = t >> 6, j = t & 63;
    if (i >= N) return;
    float acc = b[j];
#pragma unroll
    for (int k = 0; k < 5; k++) acc = fmaf(x[i * 5 + k], W[k * 64 + j], acc);
    hn[t] = dinv[i] * fmaxf(acc, 0.0f);
}

// Wave per node, float2-packed: lanes 0-31 = edge A (2 feats/lane),
// lanes 32-63 = edge B. g[i] = hn[i] + sum_{s in src(i)} hn[s].
__global__ __launch_bounds__(256) void gather2(const unsigned int* __restrict__ row_ptr,
                                               const int* __restrict__ csr_src,
                                               const float* __restrict__ hn,
                                               float* __restrict__ g, int N) {
    int t = blockIdx.x * 256 + threadIdx.x;
    int i = t >> 6;
    if (i >= N) return;
    int lane = t & 63;
    int half = lane >> 5;
    int fl = lane & 31;
    const float2* hn2 = (const float2*)hn;
    float2 acc = {0.f, 0.f}, acc2 = {0.f, 0.f};
    if (half == 0) acc = hn2[(size_t)i * 32 + fl];  // self term
    unsigned int e0 = row_ptr[i], e1 = row_ptr[i + 1];
    unsigned int ec = e1 - e0;
    unsigned int pairs = ec >> 1;
    unsigned int base = e0 + half;
    unsigned int s = 0;
    for (; s + 2 <= pairs; s += 2) {
        int s0 = csr_src[base + 2 * s];
        int s1 = csr_src[base + 2 * s + 2];
        float2 a0 = hn2[(size_t)s0 * 32 + fl];
        float2 a1 = hn2[(size_t)s1 * 32 + fl];
        acc.x += a0.x;  acc.y += a0.y;
        acc2.x += a1.x; acc2.y += a1.y;
    }
    if (s < pairs) {
        int s0 = csr_src[base + 2 * s];
        float2 a0 = hn2[(size_t)s0 * 32 + fl];
        acc.x += a0.x; acc.y += a0.y;
    }
    if ((ec & 1u) && half == 0) {  // odd remainder: half A only
        int s0 = csr_src[e1 - 1];
        float2 a0 = hn2[(size_t)s0 * 32 + fl];
        acc2.x += a0.x; acc2.y += a0.y;
    }
    acc.x += acc2.x; acc.y += acc2.y;
    acc.x += __shfl_xor(acc.x, 32, 64);
    acc.y += __shfl_xor(acc.y, 32, 64);
    if (half == 0) {
        float2* g2 = (float2*)g;
        g2[(size_t)i * 32 + fl] = acc;
    }
}

// Thread per (node, output-half). Row of g in VGPRs; W transposed in LDS
// (stride 68 floats -> 16B aligned rows, wave-uniform broadcast reads).
// hout = relu(dinv*(g@W)+b) * (scaleOut? dinv : 1)
__global__ __launch_bounds__(256) void conv_relu(const float* __restrict__ g,
                                                 const float* __restrict__ W,
                                                 const float* __restrict__ b,
                                                 const float* __restrict__ dinv,
                                                 float* __restrict__ hout,
                                                 int N, int scaleOut) {
    __shared__ float WT[64 * 68];
    int tid = threadIdx.x;
    for (int e = tid; e < 4096; e += 256) {
        int k = e >> 6, j = e & 63;
        WT[j * 68 + k] = W[e];
    }
    __syncthreads();
    int half = tid >> 7;
    int i = blockIdx.x * 128 + (tid & 127);
    if (i >= N) return;
    float4 h[16];
    const float4* g4 = (const float4*)(g + (size_t)i * 64);
#pragma unroll
    for (int q = 0; q < 16; q++) h[q] = g4[q];
    float di = dinv[i];
    float os = scaleOut ? di : 1.0f;
    int jb = half * 32;
    float* outp = hout + (size_t)i * 64 + jb;
#pragma unroll
    for (int j0 = 0; j0 < 32; j0 += 4) {
        float4 acc = {0.f, 0.f, 0.f, 0.f};
        const float* w0 = &WT[(jb + j0) * 68];
#pragma unroll
        for (int q = 0; q < 16; q++) {
            float4 hv = h[q];
            float4 wa = *(const float4*)(w0 + 0 * 68 + 4 * q);
            float4 wb = *(const float4*)(w0 + 1 * 68 + 4 * q);
            float4 wc = *(const float4*)(w0 + 2 * 68 + 4 * q);
            float4 wd = *(const float4*)(w0 + 3 * 68 + 4 * q);
            acc.x = fmaf(hv.x, wa.x, acc.x); acc.x = fmaf(hv.y, wa.y, acc.x);
            acc.x = fmaf(hv.z, wa.z, acc.x); acc.x = fmaf(hv.w, wa.w, acc.x);
            acc.y = fmaf(hv.x, wb.x, acc.y); acc.y = fmaf(hv.y, wb.y, acc.y);
            acc.y = fmaf(hv.z, wb.z, acc.y); acc.y = fmaf(hv.w, wb.w, acc.y);
            acc.z = fmaf(hv.x, wc.x, acc.z); acc.z = fmaf(hv.y, wc.y, acc.z);
            acc.z = fmaf(hv.z, wc.z, acc.z); acc.z = fmaf(hv.w, wc.w, acc.z);
            acc.w = fmaf(hv.x, wd.x, acc.w); acc.w = fmaf(hv.y, wd.y, acc.w);
            acc.w = fmaf(hv.z, wd.z, acc.w); acc.w = fmaf(hv.w, wd.w, acc.w);
        }
        float4 y;
        y.x = fmaxf(fmaf(di, acc.x, b[jb + j0 + 0]), 0.f) * os;
        y.y = fmaxf(fmaf(di, acc.y, b[jb + j0 + 1]), 0.f) * os;
        y.z = fmaxf(fmaf(di, acc.z, b[jb + j0 + 2]), 0.f) * os;
        y.w = fmaxf(fmaf(di, acc.w, b[jb + j0 + 3]), 0.f) * os;
        *(float4*)(outp + j0) = y;
    }
}

// Thread per (node, head). tid<128 -> demand, tid>=128 -> inventory.
__global__ __launch_bounds__(256) void heads2(const float* __restrict__ h,
                                              const float* __restrict__ W_d1, const float* __restrict__ b_d1,
                                              const float* __restrict__ W_d2, const float* __restrict__ b_d2,
                                              const float* __restrict__ W_i1, const float* __restrict__ b_i1,
                                              const float* __restrict__ W_i2, const float* __restrict__ b_i2,
                                              float* __restrict__ out, int N) {
    __shared__ float WT[2][32 * 68];
    int tid = threadIdx.x;
    for (int e = tid; e < 2048; e += 256) {
        int k = e >> 5, j = e & 31;
        WT[0][j * 68 + k] = W_d1[e];
        WT[1][j * 68 + k] = W_i1[e];
    }
    __syncthreads();
    int head = tid >> 7;
    int i = blockIdx.x * 128 + (tid & 127);
    if (i >= N) return;
    float4 hr[16];
    const float4* h4 = (const float4*)(h + (size_t)i * 64);
#pragma unroll
    for (int q = 0; q < 16; q++) hr[q] = h4[q];
    const float* W1T = WT[head];
    const float* b1 = head ? b_i1 : b_d1;
    const float* W2 = head ? W_i2 : W_d2;
    float o = head ? b_i2[0] : b_d2[0];
#pragma unroll
    for (int j0 = 0; j0 < 32; j0 += 4) {
        float4 acc = {b1[j0], b1[j0 + 1], b1[j0 + 2], b1[j0 + 3]};
        const float* w0 = &W1T[j0 * 68];
#pragma unroll
        for (int q = 0; q < 16; q++) {
            float4 hv = hr[q];
            float4 wa = *(const float4*)(w0 + 0 * 68 + 4 * q);
            float4 wb = *(const float4*)(w0 + 1 * 68 + 4 * q);
            float4 wc = *(const float4*)(w0 + 2 * 68 + 4 * q);
            float4 wd = *(const float4*)(w0 + 3 * 68 + 4 * q);
            acc.x = fmaf(hv.x, wa.x, acc.x); acc.x = fmaf(hv.y, wa.y, acc.x);
            acc.x = fmaf(hv.z, wa.z, acc.x); acc.x = fmaf(hv.w, wa.w, acc.x);
            acc.y = fmaf(hv.x, wb.x, acc.y); acc.y = fmaf(hv.y, wb.y, acc.y);
            acc.y = fmaf(hv.z, wb.z, acc.y); acc.y = fmaf(hv.w, wb.w, acc.y);
            acc.z = fmaf(hv.x, wc.x, acc.z); acc.z = fmaf(hv.y, wc.y, acc.z);
            acc.z = fmaf(hv.z, wc.z, acc.z); acc.z = fmaf(hv.w, wc.w, acc.z);
            acc.w = fmaf(hv.x, wd.x, acc.w); acc.w = fmaf(hv.y, wd.y, acc.w);
            acc.w = fmaf(hv.z, wd.z, acc.w); acc.w = fmaf(hv.w, wd.w, acc.w);
        }
        o = fmaf(fmaxf(acc.x, 0.f), W2[j0 + 0], o);
        o = fmaf(fmaxf(acc.y, 0.f), W2[j0 + 1], o);
        o = fmaf(fmaxf(acc.z, 0.f), W2[j0 + 2], o);
        o = fmaf(fmaxf(acc.w, 0.f), W2[j0 + 3], o);
    }
    out[(size_t)head * N + i] = o;
}

extern "C" void kernel_launch(void* const* d_in, const int* in_sizes, int n_in,
                              void* d_out, int out_size, void* d_ws, size_t ws_size,
                              hipStream_t stream) {
    const float* x      = (const float*)d_in[0];
    const int*   ei     = (const int*)d_in[1];
    const float* W_enc  = (const float*)d_in[2];
    const float* b_enc  = (const float*)d_in[3];
    const float* conv_W = (const float*)d_in[4];
    const float* conv_b = (const float*)d_in[5];
    const float* W_d1   = (const float*)d_in[6];
    const float* b_d1   = (const float*)d_in[7];
    const float* W_d2   = (const float*)d_in[8];
    const float* b_d2   = (const float*)d_in[9];
    const float* W_i1   = (const float*)d_in[10];
    const float* b_i1   = (const float*)d_in[11];
    const float* W_i2   = (const float*)d_in[12];
    const float* b_i2   = (const float*)d_in[13];

    const int N = in_sizes[0] / 5;
    const int E = in_sizes[1] / 2;

    float* bufA = (float*)d_ws;                         // hn / h
    float* bufB = bufA + (size_t)N * HDIM;              // g
    float* dinv = bufB + (size_t)N * HDIM;
    unsigned int* cnt     = (unsigned int*)(dinv + N);
    unsigned int* row_ptr = cnt + N;
    unsigned int* fillc   = row_ptr + N + 1;
    unsigned int* bsum    = fillc + N;
    int* csr_src          = (int*)(bsum + 1024);
    float* out = (float*)d_out;

    const int nodeBlocks = (N + 255) / 256;
    const int edgeBlocks = (E + 255) / 256;
    const int nwBlocks   = (N + 3) / 4;        // wave per node
    const int tnBlocks   = (N + 127) / 128;    // 2 threads per node

    // CSR build + dinv
    zero_cnt<<<nodeBlocks, 256, 0, stream>>>(cnt, N);
    count_col<<<edgeBlocks, 256, 0, stream>>>(ei + E, cnt, E);
    scan_blocks<<<nodeBlocks, 256, 0, stream>>>(cnt, bsum, N);
    scan_top<<<1, 256, 0, stream>>>(bsum, nodeBlocks);
    scan_finish<<<nodeBlocks, 256, 0, stream>>>(cnt, bsum, row_ptr, dinv, fillc, N, E);
    fill_csr<<<edgeBlocks, 256, 0, stream>>>(ei, row_ptr, fillc, csr_src, E);

    // encoder (writes hn0 = dinv*relu(xW+b))
    encoder<<<(N * HDIM + 255) / 256, 256, 0, stream>>>(x, W_enc, b_enc, dinv, bufA, N);

    // 3 GCN layers: gather (sum of hn), then matmul+relu (+dinv scale for next hn)
    for (int l = 0; l < 3; l++) {
        gather2<<<nwBlocks, 256, 0, stream>>>(row_ptr, csr_src, bufA, bufB, N);
        conv_relu<<<tnBlocks, 256, 0, stream>>>(bufB, conv_W + l * HDIM * HDIM,
                                                conv_b + l * HDIM, dinv, bufA, N,
                                                (l < 2) ? 1 : 0);
    }

    // heads
    heads2<<<tnBlocks, 256, 0, stream>>>(bufA, W_d1, b_d1, W_d2, b_d2,
                                         W_i1, b_i1, W_i2, b_i2, out, N);
}

// Round 5
// 345.969 us; speedup vs baseline: 2.2737x; 1.0515x over previous
//
#include <hip/hip_runtime.h>
#include <hip/hip_bf16.h>

// SupplyChainGNN: 3-layer GCN, N=50000, E=800000, H=64.
// Round 4: CSR build rewritten as atomic-free bucket sort (bucket = dst>>9).
//  hist (per-block LDS histograms) -> scan (exact run offsets) -> bin (full-line
//  int2 writes into private runs) -> csr (per-bucket LDS counting sort, fused
//  row_ptr/dinv). No global atomics; all scatter confined to per-block LDS or
//  single-XCD bucket spans. ebuf aliases bufA (dead until encoder).

#define HDIM 64
#define PB 128          // blocks in hist/bin passes (contiguous edge chunks)
#define NPB 512         // nodes per bucket
#define NPB_SHIFT 9

// Pass 1: histT[k*PB + p] = #edges of block p with dst in bucket k
__global__ __launch_bounds__(256) void hist_pass(const int* __restrict__ dst,
                                                 unsigned* __restrict__ histT,
                                                 int E, int NB) {
    __shared__ unsigned h[2048];
    int t = threadIdx.x, p = blockIdx.x;
    for (int k = t; k < NB; k += 256) h[k] = 0u;
    __syncthreads();
    int chunk = (E + PB - 1) / PB;
    int lo = p * chunk, hi = min(lo + chunk, E);
    for (int e = lo + t; e < hi; e += 256)
        atomicAdd(&h[dst[e] >> NPB_SHIFT], 1u);
    __syncthreads();
    for (int k = t; k < NB; k += 256) histT[k * PB + p] = h[k];
}

// Pass 2: exclusive scan of histT (bucket-major) in place; bbase[k] = bucket start.
__global__ __launch_bounds__(256) void scan_all(unsigned* __restrict__ histT,
                                                unsigned* __restrict__ bbase,
                                                int M, int NB, int E) {
    __shared__ unsigned part[256];
    int t = threadIdx.x;
    int chunk = (M + 255) / 256;
    int lo = t * chunk, hi = min(lo + chunk, M);
    unsigned s = 0;
    for (int i = lo; i < hi; i++) s += histT[i];
    part[t] = s;
    __syncthreads();
    for (int off = 1; off < 256; off <<= 1) {
        unsigned u = (t >= off) ? part[t - off] : 0u;
        __syncthreads();
        part[t] += u;
        __syncthreads();
    }
    unsigned run = part[t] - s;
    for (int i = lo; i < hi; i++) { unsigned c = histT[i]; histT[i] = run; run += c; }
    __syncthreads();
    for (int k = t; k < NB; k += 256) bbase[k] = histT[k * PB];
    if (t == 0) bbase[NB] = (unsigned)E;
}

// Pass 3: scatter (src,dst) into bucket-grouped ebuf; each (block,bucket) run is
// private and contiguous -> full-line writes, LDS cursors only.
__global__ __launch_bounds__(256) void bin_pass(const int* __restrict__ ei,
                                                const unsigned* __restrict__ histT,
                                                int2* __restrict__ ebuf,
                                                int E, int NB) {
    __shared__ unsigned cur[2048];
    int t = threadIdx.x, p = blockIdx.x;
    for (int k = t; k < NB; k += 256) cur[k] = histT[k * PB + p];
    __syncthreads();
    int chunk = (E + PB - 1) / PB;
    int lo = p * chunk, hi = min(lo + chunk, E);
    for (int e = lo + t; e < hi; e += 256) {
        int sN = ei[e];
        int dN = ei[E + e];
        unsigned pos = atomicAdd(&cur[dN >> NPB_SHIFT], 1u);
        ebuf[pos] = make_int2(sN, dN);
    }
}

// Pass 4: one block per bucket. LDS count -> LDS scan -> row_ptr/dinv fused,
// then place src into csr_src with LDS cursors (writes stay in bucket span).
__global__ __launch_bounds__(256) void csr_pass(const int2* __restrict__ ebuf,
                                                const unsigned* __restrict__ bbase,
                                                unsigned* __restrict__ row_ptr,
                                                float* __restrict__ dinv,
                                                int* __restrict__ csr_src,
                                                int N, int E, int NB) {
    __shared__ unsigned cntL[NPB];
    __shared__ unsigned sA[NPB], sB[NPB];
    int t = threadIdx.x, k = blockIdx.x;
    unsigned e0 = bbase[k], e1 = bbase[k + 1];
    int nbase = k << NPB_SHIFT;
    for (int j = t; j < NPB; j += 256) cntL[j] = 0u;
    __syncthreads();
    for (unsigned e = e0 + t; e < e1; e += 256)
        atomicAdd(&cntL[ebuf[e].y - nbase], 1u);
    __syncthreads();
    for (int j = t; j < NPB; j += 256) sA[j] = cntL[j];
    __syncthreads();
    unsigned* sp = sA; unsigned* dp = sB;
    for (int off = 1; off < NPB; off <<= 1) {
        for (int j = t; j < NPB; j += 256)
            dp[j] = sp[j] + ((j >= off) ? sp[j - off] : 0u);
        __syncthreads();
        unsigned* tmp = sp; sp = dp; dp = tmp;
    }
    // sp = inclusive scan; exclusive = sp[j] - cntL[j]; dp reused as cursors.
    for (int j = t; j < NPB; j += 256) {
        int node = nbase + j;
        if (node < N) {
            unsigned pos0 = e0 + sp[j] - cntL[j];
            row_ptr[node] = pos0;
            dinv[node] = rsqrtf((float)(cntL[j] + 1u));
            dp[j] = pos0;
        }
    }
    if (k == NB - 1 && t == 0) row_ptr[N] = (unsigned)E;
    __syncthreads();
    for (unsigned e = e0 + t; e < e1; e += 256) {
        int2 ed = ebuf[e];
        unsigned pos = atomicAdd(&dp[ed.y - nbase], 1u);
        csr_src[pos] = ed.x;
    }
}

// hn[i][j] = dinv[i] * relu(sum_k x[i][k]*W[k][j] + b[j]); x:[N,5]
__global__ __launch_bounds__(256) void encoder(const float* __restrict__ x,
                                               const float* __restrict__ W,
                                               const float* __restrict__ b,
                                               const float* __restrict__ dinv,
                                               float* __restrict__ hn, int N) {
    int t = blockIdx.x * 256 + threadIdx.x;
    int i = t >> 6, j = t & 63;
    if (i >= N) return;
    float acc = b[j];
#pragma unroll
    for (int k = 0; k < 5; k++) acc = fmaf(x[i * 5 + k], W[k * 64 + j], acc);
    hn[t] = dinv[i] * fmaxf(acc, 0.0f);
}

// Wave per node, float2-packed: lanes 0-31 = edge A (2 feats/lane),
// lanes 32-63 = edge B. g[i] = hn[i] + sum_{s in src(i)} hn[s].
__global__ __launch_bounds__(256) void gather2(const unsigned int* __restrict__ row_ptr,
                                               const int* __restrict__ csr_src,
                                               const float* __restrict__ hn,
                                               float* __restrict__ g, int N) {
    int t = blockIdx.x * 256 + threadIdx.x;
    int i = t >> 6;
    if (i >= N) return;
    int lane = t & 63;
    int half = lane >> 5;
    int fl = lane & 31;
    const float2* hn2 = (const float2*)hn;
    float2 acc = {0.f, 0.f}, acc2 = {0.f, 0.f};
    if (half == 0) acc = hn2[(size_t)i * 32 + fl];  // self term
    unsigned int e0 = row_ptr[i], e1 = row_ptr[i + 1];
    unsigned int ec = e1 - e0;
    unsigned int pairs = ec >> 1;
    unsigned int base = e0 + half;
    unsigned int s = 0;
    for (; s + 2 <= pairs; s += 2) {
        int s0 = csr_src[base + 2 * s];
        int s1 = csr_src[base + 2 * s + 2];
        float2 a0 = hn2[(size_t)s0 * 32 + fl];
        float2 a1 = hn2[(size_t)s1 * 32 + fl];
        acc.x += a0.x;  acc.y += a0.y;
        acc2.x += a1.x; acc2.y += a1.y;
    }
    if (s < pairs) {
        int s0 = csr_src[base + 2 * s];
        float2 a0 = hn2[(size_t)s0 * 32 + fl];
        acc.x += a0.x; acc.y += a0.y;
    }
    if ((ec & 1u) && half == 0) {
        int s0 = csr_src[e1 - 1];
        float2 a0 = hn2[(size_t)s0 * 32 + fl];
        acc2.x += a0.x; acc2.y += a0.y;
    }
    acc.x += acc2.x; acc.y += acc2.y;
    acc.x += __shfl_xor(acc.x, 32, 64);
    acc.y += __shfl_xor(acc.y, 32, 64);
    if (half == 0) {
        float2* g2 = (float2*)g;
        g2[(size_t)i * 32 + fl] = acc;
    }
}

// Thread per (node, output-half). Row of g in VGPRs; W transposed in LDS
// (stride 68 -> 16B aligned, wave-uniform broadcast ds_read_b128).
__global__ __launch_bounds__(256) void conv_relu(const float* __restrict__ g,
                                                 const float* __restrict__ W,
                                                 const float* __restrict__ b,
                                                 const float* __restrict__ dinv,
                                                 float* __restrict__ hout,
                                                 int N, int scaleOut) {
    __shared__ float WT[64 * 68];
    int tid = threadIdx.x;
    for (int e = tid; e < 4096; e += 256) {
        int k = e >> 6, j = e & 63;
        WT[j * 68 + k] = W[e];
    }
    __syncthreads();
    int half = tid >> 7;
    int i = blockIdx.x * 128 + (tid & 127);
    if (i >= N) return;
    float4 h[16];
    const float4* g4 = (const float4*)(g + (size_t)i * 64);
#pragma unroll
    for (int q = 0; q < 16; q++) h[q] = g4[q];
    float di = dinv[i];
    float os = scaleOut ? di : 1.0f;
    int jb = half * 32;
    float* outp = hout + (size_t)i * 64 + jb;
#pragma unroll
    for (int j0 = 0; j0 < 32; j0 += 4) {
        float4 acc = {0.f, 0.f, 0.f, 0.f};
        const float* w0 = &WT[(jb + j0) * 68];
#pragma unroll
        for (int q = 0; q < 16; q++) {
            float4 hv = h[q];
            float4 wa = *(const float4*)(w0 + 0 * 68 + 4 * q);
            float4 wb = *(const float4*)(w0 + 1 * 68 + 4 * q);
            float4 wc = *(const float4*)(w0 + 2 * 68 + 4 * q);
            float4 wd = *(const float4*)(w0 + 3 * 68 + 4 * q);
            acc.x = fmaf(hv.x, wa.x, acc.x); acc.x = fmaf(hv.y, wa.y, acc.x);
            acc.x = fmaf(hv.z, wa.z, acc.x); acc.x = fmaf(hv.w, wa.w, acc.x);
            acc.y = fmaf(hv.x, wb.x, acc.y); acc.y = fmaf(hv.y, wb.y, acc.y);
            acc.y = fmaf(hv.z, wb.z, acc.y); acc.y = fmaf(hv.w, wb.w, acc.y);
            acc.z = fmaf(hv.x, wc.x, acc.z); acc.z = fmaf(hv.y, wc.y, acc.z);
            acc.z = fmaf(hv.z, wc.z, acc.z); acc.z = fmaf(hv.w, wc.w, acc.z);
            acc.w = fmaf(hv.x, wd.x, acc.w); acc.w = fmaf(hv.y, wd.y, acc.w);
            acc.w = fmaf(hv.z, wd.z, acc.w); acc.w = fmaf(hv.w, wd.w, acc.w);
        }
        float4 y;
        y.x = fmaxf(fmaf(di, acc.x, b[jb + j0 + 0]), 0.f) * os;
        y.y = fmaxf(fmaf(di, acc.y, b[jb + j0 + 1]), 0.f) * os;
        y.z = fmaxf(fmaf(di, acc.z, b[jb + j0 + 2]), 0.f) * os;
        y.w = fmaxf(fmaf(di, acc.w, b[jb + j0 + 3]), 0.f) * os;
        *(float4*)(outp + j0) = y;
    }
}

// Thread per (node, head). tid<128 -> demand, tid>=128 -> inventory.
__global__ __launch_bounds__(256) void heads2(const float* __restrict__ h,
                                              const float* __restrict__ W_d1, const float* __restrict__ b_d1,
                                              const float* __restrict__ W_d2, const float* __restrict__ b_d2,
                                              const float* __restrict__ W_i1, const float* __restrict__ b_i1,
                                              const float* __restrict__ W_i2, const float* __restrict__ b_i2,
                                              float* __restrict__ out, int N) {
    __shared__ float WT[2][32 * 68];
    int tid = threadIdx.x;
    for (int e = tid; e < 2048; e += 256) {
        int k = e >> 5, j = e & 31;
        WT[0][j * 68 + k] = W_d1[e];
        WT[1][j * 68 + k] = W_i1[e];
    }
    __syncthreads();
    int head = tid >> 7;
    int i = blockIdx.x * 128 + (tid & 127);
    if (i >= N) return;
    float4 hr[16];
    const float4* h4 = (const float4*)(h + (size_t)i * 64);
#pragma unroll
    for (int q = 0; q < 16; q++) hr[q] = h4[q];
    const float* W1T = WT[head];
    const float* b1 = head ? b_i1 : b_d1;
    const float* W2 = head ? W_i2 : W_d2;
    float o = head ? b_i2[0] : b_d2[0];
#pragma unroll
    for (int j0 = 0; j0 < 32; j0 += 4) {
        float4 acc = {b1[j0], b1[j0 + 1], b1[j0 + 2], b1[j0 + 3]};
        const float* w0 = &W1T[j0 * 68];
#pragma unroll
        for (int q = 0; q < 16; q++) {
            float4 hv = hr[q];
            float4 wa = *(const float4*)(w0 + 0 * 68 + 4 * q);
            float4 wb = *(const float4*)(w0 + 1 * 68 + 4 * q);
            float4 wc = *(const float4*)(w0 + 2 * 68 + 4 * q);
            float4 wd = *(const float4*)(w0 + 3 * 68 + 4 * q);
            acc.x = fmaf(hv.x, wa.x, acc.x); acc.x = fmaf(hv.y, wa.y, acc.x);
            acc.x = fmaf(hv.z, wa.z, acc.x); acc.x = fmaf(hv.w, wa.w, acc.x);
            acc.y = fmaf(hv.x, wb.x, acc.y); acc.y = fmaf(hv.y, wb.y, acc.y);
            acc.y = fmaf(hv.z, wb.z, acc.y); acc.y = fmaf(hv.w, wb.w, acc.y);
            acc.z = fmaf(hv.x, wc.x, acc.z); acc.z = fmaf(hv.y, wc.y, acc.z);
            acc.z = fmaf(hv.z, wc.z, acc.z); acc.z = fmaf(hv.w, wc.w, acc.z);
            acc.w = fmaf(hv.x, wd.x, acc.w); acc.w = fmaf(hv.y, wd.y, acc.w);
            acc.w = fmaf(hv.z, wd.z, acc.w); acc.w = fmaf(hv.w, wd.w, acc.w);
        }
        o = fmaf(fmaxf(acc.x, 0.f), W2[j0 + 0], o);
        o = fmaf(fmaxf(acc.y, 0.f), W2[j0 + 1], o);
        o = fmaf(fmaxf(acc.z, 0.f), W2[j0 + 2], o);
        o = fmaf(fmaxf(acc.w, 0.f), W2[j0 + 3], o);
    }
    out[(size_t)head * N + i] = o;
}

extern "C" void kernel_launch(void* const* d_in, const int* in_sizes, int n_in,
                              void* d_out, int out_size, void* d_ws, size_t ws_size,
                              hipStream_t stream) {
    const float* x      = (const float*)d_in[0];
    const int*   ei     = (const int*)d_in[1];
    const float* W_enc  = (const float*)d_in[2];
    const float* b_enc  = (const float*)d_in[3];
    const float* conv_W = (const float*)d_in[4];
    const float* conv_b = (const float*)d_in[5];
    const float* W_d1   = (const float*)d_in[6];
    const float* b_d1   = (const float*)d_in[7];
    const float* W_d2   = (const float*)d_in[8];
    const float* b_d2   = (const float*)d_in[9];
    const float* W_i1   = (const float*)d_in[10];
    const float* b_i1   = (const float*)d_in[11];
    const float* W_i2   = (const float*)d_in[12];
    const float* b_i2   = (const float*)d_in[13];

    const int N = in_sizes[0] / 5;
    const int E = in_sizes[1] / 2;
    const int NB = (N + NPB - 1) >> NPB_SHIFT;   // buckets

    float* bufA = (float*)d_ws;                         // hn / h  (ebuf aliases)
    float* bufB = bufA + (size_t)N * HDIM;              // g
    float* dinv = bufB + (size_t)N * HDIM;
    unsigned int* row_ptr = (unsigned int*)(dinv + N);  // [N+1]
    unsigned int* histT   = row_ptr + N + 1;            // [NB*PB]
    unsigned int* bbase   = histT + (size_t)NB * PB;    // [NB+1]
    int* csr_src          = (int*)(bbase + NB + 1);     // [E]
    int2* ebuf            = (int2*)bufA;                // [E] (dead before encoder)
    float* out = (float*)d_out;

    const int nwBlocks = (N + 3) / 4;        // wave per node
    const int tnBlocks = (N + 127) / 128;    // 2 threads per node

    // CSR build: bucket sort, no global atomics
    hist_pass<<<PB, 256, 0, stream>>>(ei + E, histT, E, NB);
    scan_all<<<1, 256, 0, stream>>>(histT, bbase, NB * PB, NB, E);
    bin_pass<<<PB, 256, 0, stream>>>(ei, histT, ebuf, E, NB);
    csr_pass<<<NB, 256, 0, stream>>>(ebuf, bbase, row_ptr, dinv, csr_src, N, E, NB);

    // encoder (writes hn0 = dinv*relu(xW+b)) -- reuses bufA after ebuf is consumed
    encoder<<<(N * HDIM + 255) / 256, 256, 0, stream>>>(x, W_enc, b_enc, dinv, bufA, N);

    // 3 GCN layers
    for (int l = 0; l < 3; l++) {
        gather2<<<nwBlocks, 256, 0, stream>>>(row_ptr, csr_src, bufA, bufB, N);
        conv_relu<<<tnBlocks, 256, 0, stream>>>(bufB, conv_W + l * HDIM * HDIM,
                                                conv_b + l * HDIM, dinv, bufA, N,
                                                (l < 2) ? 1 : 0);
    }

    // heads
    heads2<<<tnBlocks, 256, 0, stream>>>(bufA, W_d1, b_d1, W_d2, b_d2,
                                         W_i1, b_i1, W_i2, b_i2, out, N);
}